// Round 1
// baseline (1686.395 us; speedup 1.0000x reference)
//
#include <hip/hip_runtime.h>

#define Bq 2
#define Cc 128
#define Gg 16
#define CPG 8
#define Hh 64
#define Ww 64
#define NP 81
#define TP 9
#define OC 64

// ---------------- correlation + leaky relu ----------------
// grid (4, 64, 2), block (64, 4): g = bx*4+ty, y = by, b = bz, x = tx
__global__ __launch_bounds__(256) void corr_kernel(
    const float* __restrict__ x1, const float* __restrict__ x2,
    float* __restrict__ cost, int dil)
{
    const int tx = threadIdx.x;
    const int g  = blockIdx.x * 4 + threadIdx.y;
    const int y  = blockIdx.y;
    const int b  = blockIdx.z;

    const size_t chw = (size_t)Cc * Hh * Ww;
    const size_t ghw = (size_t)Gg * Hh * Ww;   // channel-k stride within a group
    const float* x1b = x1 + (size_t)b * chw + (size_t)g * Hh * Ww;
    const float* x2b = x2 + (size_t)b * chw + (size_t)g * Hh * Ww;

    float a1[CPG];
#pragma unroll
    for (int k = 0; k < CPG; ++k)
        a1[k] = x1b[k * ghw + y * Ww + tx];

    float* cb = cost + (((size_t)b * Gg + g) * NP) * Hh * Ww + y * Ww + tx;

    for (int i = 0; i < 9; ++i) {
        const int yy = y + (i - 4) * dil;
        const bool yok = (unsigned)yy < (unsigned)Hh;
#pragma unroll
        for (int j = 0; j < 9; ++j) {
            const int xx = tx + (j - 4) * dil;
            float s = 0.f;
            if (yok && ((unsigned)xx < (unsigned)Ww)) {
                const float* p2 = x2b + yy * Ww + xx;
#pragma unroll
                for (int k = 0; k < CPG; ++k)
                    s = fmaf(a1[k], p2[k * ghw], s);
            }
            s = s > 0.f ? s : 0.1f * s;   // leaky relu 0.1
            cb[(size_t)(i * 9 + j) * Hh * Ww] = s;
        }
    }
}

// ---------------- conv3d 3x3x3 (16->16) + bias + BN + ReLU ----------------
// grid (9, 64, 2 or 8), block (64, 4).
// block owns: (b, d) from z, y from by, p-tile [p0, p0+9) from bx.
// thread owns: x = tx, 4 output channels go = ty*4+q; acc[9][4].
__global__ __launch_bounds__(256) void conv_kernel(
    const float* __restrict__ cost, size_t cost_dstride,
    const float* __restrict__ w_all, const float* __restrict__ bias_all,
    const float* __restrict__ gamma_all, const float* __restrict__ beta_all,
    const float* __restrict__ mean_all, const float* __restrict__ var_all,
    float* __restrict__ out, int d_idx_param)
{
    int d_idx, b;
    if (gridDim.z == 8) { d_idx = blockIdx.z >> 1; b = blockIdx.z & 1; }
    else                { d_idx = d_idx_param;     b = blockIdx.z; }

    const int tx = threadIdx.x;          // x
    const int ty = threadIdx.y;          // go quad (uniform per wave: blockDim.x==64)
    const int y  = blockIdx.y;
    const int p0 = blockIdx.x * TP;
    const int tid = ty * 64 + tx;

    __shared__ float wl[Gg * Gg * 27];           // 27.6 KB, whole dilation's weights
    __shared__ float inl[TP + 2][3][Ww + 2];     // 8.7 KB, one gi plane w/ halo

    const float* wd = w_all + (size_t)d_idx * Gg * Gg * 27;
    for (int idx = tid; idx < Gg * Gg * 27; idx += 256)
        wl[idx] = wd[idx];

    // fused bias+BN constants:  final = max(0, acc*scale + off)
    float scale[4], off[4];
#pragma unroll
    for (int q = 0; q < 4; ++q) {
        const int go = ty * 4 + q;
        const float gmm = gamma_all[d_idx * Gg + go];
        const float bta = beta_all [d_idx * Gg + go];
        const float mu  = mean_all [d_idx * Gg + go];
        const float vr  = var_all  [d_idx * Gg + go];
        const float bs  = bias_all [d_idx * Gg + go];
        const float inv = gmm * rsqrtf(vr + 1e-5f);
        scale[q] = inv;
        off[q]   = (bs - mu) * inv + bta;
    }

    const float* cb = cost + (size_t)d_idx * cost_dstride
                           + (size_t)b * Gg * NP * Hh * Ww;

    float acc[TP][4];
#pragma unroll
    for (int p = 0; p < TP; ++p)
#pragma unroll
        for (int q = 0; q < 4; ++q) acc[p][q] = 0.f;

    for (int gi = 0; gi < Gg; ++gi) {
        __syncthreads();
        // stage [11][3][66] input plane for this gi (zero-padded halo)
        const float* cg = cb + (size_t)gi * NP * Hh * Ww;
#pragma unroll
        for (int it = 0; it < 9; ++it) {
            const int idx = tid + it * 256;
            if (idx < (TP + 2) * 3 * (Ww + 2)) {
                const int xx = idx % (Ww + 2);
                const int r  = idx / (Ww + 2);
                const int yy = r % 3;
                const int pp = r / 3;
                const int gp = p0 + pp - 1;
                const int gy = y + yy - 1;
                const int gx = xx - 1;
                float v = 0.f;
                if ((unsigned)gp < (unsigned)NP && (unsigned)gy < (unsigned)Hh &&
                    (unsigned)gx < (unsigned)Ww)
                    v = cg[((size_t)gp * Hh + gy) * Ww + gx];
                inl[pp][yy][xx] = v;
            }
        }
        __syncthreads();

#pragma unroll
        for (int dp = 0; dp < 3; ++dp)
#pragma unroll
        for (int dy = 0; dy < 3; ++dy)
#pragma unroll
        for (int dx = 0; dx < 3; ++dx) {
            const int tap = (dp * 3 + dy) * 3 + dx;
            const float w0 = wl[((ty * 4 + 0) * Gg + gi) * 27 + tap];
            const float w1 = wl[((ty * 4 + 1) * Gg + gi) * 27 + tap];
            const float w2 = wl[((ty * 4 + 2) * Gg + gi) * 27 + tap];
            const float w3 = wl[((ty * 4 + 3) * Gg + gi) * 27 + tap];
#pragma unroll
            for (int p = 0; p < TP; ++p) {
                const float v = inl[p + dp][dy][tx + dx];
                acc[p][0] = fmaf(w0, v, acc[p][0]);
                acc[p][1] = fmaf(w1, v, acc[p][1]);
                acc[p][2] = fmaf(w2, v, acc[p][2]);
                acc[p][3] = fmaf(w3, v, acc[p][3]);
            }
        }
    }

    // epilogue: bias+BN+ReLU, store to concat layout [b][d*16+go][p][y][x]
#pragma unroll
    for (int p = 0; p < TP; ++p) {
#pragma unroll
        for (int q = 0; q < 4; ++q) {
            const int go = ty * 4 + q;
            float v = fmaf(acc[p][q], scale[q], off[q]);
            v = v > 0.f ? v : 0.f;
            out[((((size_t)b * OC + d_idx * Gg + go) * NP + (p0 + p)) * Hh + y) * Ww + tx] = v;
        }
    }
}

extern "C" void kernel_launch(void* const* d_in, const int* in_sizes, int n_in,
                              void* d_out, int out_size, void* d_ws, size_t ws_size,
                              hipStream_t stream) {
    const float* x    = (const float*)d_in[0];
    const float* nbx  = (const float*)d_in[1];
    const float* cw   = (const float*)d_in[2];
    const float* cbia = (const float*)d_in[3];
    const float* gam  = (const float*)d_in[4];
    const float* bet  = (const float*)d_in[5];
    const float* mea  = (const float*)d_in[6];
    const float* var  = (const float*)d_in[7];
    float* out = (float*)d_out;
    float* ws  = (float*)d_ws;

    const size_t COST = (size_t)Bq * Gg * NP * Hh * Ww;   // 10,616,832 elems (42.5 MB)
    const int dils[4] = {1, 2, 4, 8};
    const bool big = ws_size >= 4 * COST * sizeof(float);

    if (big) {
        // all 4 cost volumes in ws, then one merged conv launch (less tail waste)
        for (int d = 0; d < 4; ++d)
            corr_kernel<<<dim3(4, 64, 2), dim3(64, 4), 0, stream>>>(
                x, nbx, ws + d * COST, dils[d]);
        conv_kernel<<<dim3(NP / TP, 64, 8), dim3(64, 4), 0, stream>>>(
            ws, COST, cw, cbia, gam, bet, mea, var, out, 0);
    } else {
        for (int d = 0; d < 4; ++d) {
            corr_kernel<<<dim3(4, 64, 2), dim3(64, 4), 0, stream>>>(
                x, nbx, ws, dils[d]);
            conv_kernel<<<dim3(NP / TP, 64, 2), dim3(64, 4), 0, stream>>>(
                ws, 0, cw, cbia, gam, bet, mea, var, out, d);
        }
    }
}

// Round 4
// 943.820 us; speedup vs baseline: 1.7868x; 1.7868x over previous
//
#include <hip/hip_runtime.h>

#define Bq 2
#define Cc 128
#define Gg 16
#define CPG 8
#define Hh 64
#define Ww 64
#define NP 81
#define TP 9
#define OC 64
#define PLANE ((TP + 2) * 3 * (Ww + 2))   // 11*3*66 = 2178 floats

// ---------------- correlation + leaky relu ----------------
// grid (4, 64, 2), block (64, 4): g = bx*4+ty, y = by, b = bz, x = tx
__global__ __launch_bounds__(256) void corr_kernel(
    const float* __restrict__ x1, const float* __restrict__ x2,
    float* __restrict__ cost, int dil)
{
    const int tx = threadIdx.x;
    const int g  = blockIdx.x * 4 + threadIdx.y;
    const int y  = blockIdx.y;
    const int b  = blockIdx.z;

    const size_t chw = (size_t)Cc * Hh * Ww;
    const size_t ghw = (size_t)Gg * Hh * Ww;   // channel-k stride within a group
    const float* x1b = x1 + (size_t)b * chw + (size_t)g * Hh * Ww;
    const float* x2b = x2 + (size_t)b * chw + (size_t)g * Hh * Ww;

    float a1[CPG];
#pragma unroll
    for (int k = 0; k < CPG; ++k)
        a1[k] = x1b[k * ghw + y * Ww + tx];

    float* cb = cost + (((size_t)b * Gg + g) * NP) * Hh * Ww + y * Ww + tx;

    for (int i = 0; i < 9; ++i) {
        const int yy = y + (i - 4) * dil;
        const bool yok = (unsigned)yy < (unsigned)Hh;
#pragma unroll
        for (int j = 0; j < 9; ++j) {
            const int xx = tx + (j - 4) * dil;
            float s = 0.f;
            if (yok && ((unsigned)xx < (unsigned)Ww)) {
                const float* p2 = x2b + yy * Ww + xx;
#pragma unroll
                for (int k = 0; k < CPG; ++k)
                    s = fmaf(a1[k], p2[k * ghw], s);
            }
            s = s > 0.f ? s : 0.1f * s;   // leaky relu 0.1
            cb[(size_t)(i * 9 + j) * Hh * Ww] = s;
        }
    }
}

// ---------------- conv3d 3x3x3 (16->16) + bias + BN + ReLU ----------------
// grid (9, 64, 2 or 8), block (64, 4).
// block owns: (b, d) from z, y from by, p-tile [p0, p0+9) from bx.
// thread owns: x = tx, 4 output channels go = ty*4+q; acc[9][4].
// Double-buffered per-gi staging: issue gi+1 loads -> compute gi -> ds_write
// gi+1 -> one barrier. Weights relayout [gi][tap][go] for b128 broadcast.
__global__ __launch_bounds__(256) void conv_kernel(
    const float* __restrict__ cost, size_t cost_dstride,
    const float* __restrict__ w_all, const float* __restrict__ bias_all,
    const float* __restrict__ gamma_all, const float* __restrict__ beta_all,
    const float* __restrict__ mean_all, const float* __restrict__ var_all,
    float* __restrict__ out, int d_idx_param)
{
    int d_idx, b;
    if (gridDim.z == 8) { d_idx = blockIdx.z >> 1; b = blockIdx.z & 1; }
    else                { d_idx = d_idx_param;     b = blockIdx.z; }

    const int tx = threadIdx.x;          // x
    const int ty = threadIdx.y;          // go quad (uniform per wave)
    const int y  = blockIdx.y;
    const int p0 = blockIdx.x * TP;
    const int tid = ty * 64 + tx;

    __shared__ float wl[Gg * 27 * Gg];   // [gi][tap][go], 27.6 KB
    __shared__ float inl[2][PLANE];      // double-buffered plane, 17.4 KB

    // weights: global [go][gi][tap] -> LDS [gi][tap][go]
    const float* wd = w_all + (size_t)d_idx * Gg * Gg * 27;
    for (int idx = tid; idx < Gg * Gg * 27; idx += 256) {
        const int go  = idx & 15;
        const int r   = idx >> 4;
        const int tap = r % 27;
        const int gi  = r / 27;
        wl[idx] = wd[(go * Gg + gi) * 27 + tap];
    }

    // fused bias+BN constants:  final = max(0, acc*scale + off)
    float scale[4], off[4];
#pragma unroll
    for (int q = 0; q < 4; ++q) {
        const int go = ty * 4 + q;
        const float gmm = gamma_all[d_idx * Gg + go];
        const float bta = beta_all [d_idx * Gg + go];
        const float mu  = mean_all [d_idx * Gg + go];
        const float vr  = var_all  [d_idx * Gg + go];
        const float bs  = bias_all [d_idx * Gg + go];
        const float inv = gmm * rsqrtf(vr + 1e-5f);
        scale[q] = inv;
        off[q]   = (bs - mu) * inv + bta;
    }

    // gi-invariant staging offsets/validity (9 values per thread)
    int  offs[9];
    bool vld[9];
#pragma unroll
    for (int it = 0; it < 9; ++it) {
        const int idx = tid + it * 256;
        const int xx = idx % (Ww + 2);
        const int r  = idx / (Ww + 2);
        const int yy = r % 3;
        const int pp = r / 3;
        const int gp = p0 + pp - 1;
        const int gy = y + yy - 1;
        const int gx = xx - 1;
        vld[it] = (idx < PLANE) && ((unsigned)gp < (unsigned)NP) &&
                  ((unsigned)gy < (unsigned)Hh) && ((unsigned)gx < (unsigned)Ww);
        offs[it] = (gp * Hh + gy) * Ww + gx;
    }

    const float* cb = cost + (size_t)d_idx * cost_dstride
                           + (size_t)b * Gg * NP * Hh * Ww;

    float acc[TP][4];
#pragma unroll
    for (int p = 0; p < TP; ++p)
#pragma unroll
        for (int q = 0; q < 4; ++q) acc[p][q] = 0.f;

    // prologue: stage gi=0 into buffer 0
    {
        const float* cg = cb;
#pragma unroll
        for (int it = 0; it < 9; ++it) {
            const int idx = tid + it * 256;
            float v = vld[it] ? cg[offs[it]] : 0.f;
            if (idx < PLANE) inl[0][idx] = v;
        }
    }
    __syncthreads();

    int cur = 0;
#pragma unroll 1
    for (int gi = 0; gi < Gg; ++gi) {
        // 1) issue prefetch loads for gi+1 (latency hides under compute)
        float pf[9];
        if (gi < Gg - 1) {
            const float* cg = cb + (size_t)(gi + 1) * NP * Hh * Ww;
#pragma unroll
            for (int it = 0; it < 9; ++it)
                pf[it] = vld[it] ? cg[offs[it]] : 0.f;
        }

        // 2) compute gi from inl[cur]
        const float* __restrict__ plane = inl[cur];
        const float* __restrict__ wg = &wl[gi * 27 * Gg + ty * 4];
#pragma unroll
        for (int dy = 0; dy < 3; ++dy) {
#pragma unroll
            for (int dx = 0; dx < 3; ++dx) {
                float col[TP + 2];
#pragma unroll
                for (int pp = 0; pp < TP + 2; ++pp)
                    col[pp] = plane[(pp * 3 + dy) * (Ww + 2) + tx + dx];
#pragma unroll
                for (int dp = 0; dp < 3; ++dp) {
                    const int tap = (dp * 3 + dy) * 3 + dx;
                    const float4 wv = *(const float4*)&wg[tap * Gg];
#pragma unroll
                    for (int p = 0; p < TP; ++p) {
                        const float v = col[p + dp];
                        acc[p][0] = fmaf(wv.x, v, acc[p][0]);
                        acc[p][1] = fmaf(wv.y, v, acc[p][1]);
                        acc[p][2] = fmaf(wv.z, v, acc[p][2]);
                        acc[p][3] = fmaf(wv.w, v, acc[p][3]);
                    }
                }
            }
        }

        // 3) write prefetch into the other buffer, 4) single barrier, flip
        if (gi < Gg - 1) {
            float* dst = inl[cur ^ 1];
#pragma unroll
            for (int it = 0; it < 9; ++it) {
                const int idx = tid + it * 256;
                if (idx < PLANE) dst[idx] = pf[it];
            }
            __syncthreads();
            cur ^= 1;
        }
    }

    // epilogue: bias+BN+ReLU, store to concat layout [b][d*16+go][p][y][x]
#pragma unroll
    for (int p = 0; p < TP; ++p) {
#pragma unroll
        for (int q = 0; q < 4; ++q) {
            const int go = ty * 4 + q;
            float v = fmaf(acc[p][q], scale[q], off[q]);
            v = v > 0.f ? v : 0.f;
            out[((((size_t)b * OC + d_idx * Gg + go) * NP + (p0 + p)) * Hh + y) * Ww + tx] = v;
        }
    }
}

extern "C" void kernel_launch(void* const* d_in, const int* in_sizes, int n_in,
                              void* d_out, int out_size, void* d_ws, size_t ws_size,
                              hipStream_t stream) {
    const float* x    = (const float*)d_in[0];
    const float* nbx  = (const float*)d_in[1];
    const float* cw   = (const float*)d_in[2];
    const float* cbia = (const float*)d_in[3];
    const float* gam  = (const float*)d_in[4];
    const float* bet  = (const float*)d_in[5];
    const float* mea  = (const float*)d_in[6];
    const float* var  = (const float*)d_in[7];
    float* out = (float*)d_out;
    float* ws  = (float*)d_ws;

    const size_t COST = (size_t)Bq * Gg * NP * Hh * Ww;   // 10,616,832 elems (42.5 MB)
    const int dils[4] = {1, 2, 4, 8};
    const bool big = ws_size >= 4 * COST * sizeof(float);

    if (big) {
        // all 4 cost volumes in ws, then one merged conv launch
        for (int d = 0; d < 4; ++d)
            corr_kernel<<<dim3(4, 64, 2), dim3(64, 4), 0, stream>>>(
                x, nbx, ws + d * COST, dils[d]);
        conv_kernel<<<dim3(NP / TP, 64, 8), dim3(64, 4), 0, stream>>>(
            ws, COST, cw, cbia, gam, bet, mea, var, out, 0);
    } else {
        for (int d = 0; d < 4; ++d) {
            corr_kernel<<<dim3(4, 64, 2), dim3(64, 4), 0, stream>>>(
                x, nbx, ws, dils[d]);
            conv_kernel<<<dim3(NP / TP, 64, 2), dim3(64, 4), 0, stream>>>(
                ws, 0, cw, cbia, gam, bet, mea, var, out, d);
        }
    }
}

// Round 6
// 348.555 us; speedup vs baseline: 4.8382x; 2.7078x over previous
//
#include <hip/hip_runtime.h>

typedef short short8v __attribute__((ext_vector_type(8)));
typedef float f32x4  __attribute__((ext_vector_type(4)));

#define NP    81
#define P2    83
#define Y2    66
#define X2    66
#define PIX2  (Y2*X2)             // 4356 pixels per padded (y,x) plane
#define SLABE ((long)P2*PIX2*16)  // bf16 elems per (b,d) slab = 5,784,768
#define LDS_BYTES 73728           // 4608 chunks of 16B (tile 11*3*66 pix * 32B = 69,696, rounded up)

// round-to-nearest-even f32 -> bf16
__device__ __forceinline__ unsigned short f2bf(float f){
  union{float f; unsigned u;} v; v.f=f;
  return (unsigned short)((v.u + 0x7FFFu + ((v.u>>16)&1u))>>16);
}

// ---------------- zero the halo borders of all 8 padded slabs ----------------
__global__ void zero_border(unsigned short* __restrict__ ws){
  int idx=blockIdx.x*256+threadIdx.x;
  const int tot=8*P2*PIX2;
  if(idx>=tot) return;
  int slab=idx/(P2*PIX2);
  int pix=idx-slab*(P2*PIX2);
  int p=pix/PIX2;
  int r=pix-p*PIX2;
  int yv=r/X2, xv=r-yv*X2;
  if(p==0||p==P2-1||yv==0||yv==Y2-1||xv==0||xv==X2-1){
    uint4 z={0u,0u,0u,0u};
    uint4* dst=(uint4*)(ws+(long)slab*SLABE+(long)pix*16);
    dst[0]=z; dst[1]=z;
  }
}

// ---------------- correlation + leaky relu -> bf16 NHWC padded ----------------
// grid (64 y, 8 bd, 3 iseg), block (64,4): tx=x, ty=g-quad
__global__ __launch_bounds__(256) void corr_kernel(
    const float* __restrict__ x1, const float* __restrict__ x2,
    unsigned short* __restrict__ ws)
{
  const int tx=threadIdx.x, ty=threadIdx.y;
  const int y=blockIdx.x;
  const int bd=blockIdx.y, b=bd&1, d=bd>>1;
  const int dil=1<<d;                    // 1,2,4,8
  const int i0=blockIdx.z*3;
  const int g0=ty*4;
  const float* x1b = x1 + (long)b*128*4096 + (long)g0*4096 + y*64 + tx;
  const float* x2b = x2 + (long)b*128*4096 + (long)g0*4096;
  float a1[8][4];
#pragma unroll
  for(int k=0;k<8;++k)
#pragma unroll
    for(int q=0;q<4;++q)
      a1[k][q]=x1b[(k*16+q)*4096];       // channel c = k*16 + g0+q
  unsigned short* sp = ws + (long)bd*SLABE;
  for(int i=i0;i<i0+3;++i){
    const int yy=y+(i-4)*dil;
    const bool yok=(unsigned)yy<64u;
#pragma unroll
    for(int j=0;j<9;++j){
      const int xx=tx+(j-4)*dil;
      float s0=0.f,s1=0.f,s2=0.f,s3=0.f;
      if(yok&&((unsigned)xx<64u)){
        const float* p2=x2b+yy*64+xx;
#pragma unroll
        for(int k=0;k<8;++k){
          s0=fmaf(a1[k][0],p2[(k*16+0)*4096],s0);
          s1=fmaf(a1[k][1],p2[(k*16+1)*4096],s1);
          s2=fmaf(a1[k][2],p2[(k*16+2)*4096],s2);
          s3=fmaf(a1[k][3],p2[(k*16+3)*4096],s3);
        }
      }
      const int p=i*9+j;
      const long pix=(long)(p+1)*PIX2+(long)(y+1)*X2+(tx+1);
      ushort4 o;
      o.x=f2bf(s0>0.f?s0:0.1f*s0);
      o.y=f2bf(s1>0.f?s1:0.1f*s1);
      o.z=f2bf(s2>0.f?s2:0.1f*s2);
      o.w=f2bf(s3>0.f?s3:0.1f*s3);
      *(ushort4*)(sp+pix*16+g0)=o;
    }
  }
}

// ---------------- conv3d as implicit GEMM on MFMA + bias/BN/ReLU ----------------
// grid (9 ptile, 64 y, 8 bd), block 256 (4 waves, wave owns x-quarter).
// A tile: [11 pp][3 yy][66 xx][16 gi] bf16 staged linearly via global_load_lds,
// XOR-swizzled (bits[6:4] ^= bits[9:7]) for conflict-free ds_read_b128.
// B: 14 K-step fragments (K = tap*16+gi, 432 padded to 448) in VGPRs.
__global__ __launch_bounds__(256,2) void conv_mfma(
    const unsigned short* __restrict__ ws,
    const float* __restrict__ w_all, const float* __restrict__ bias_all,
    const float* __restrict__ gamma_all, const float* __restrict__ beta_all,
    const float* __restrict__ mean_all, const float* __restrict__ var_all,
    float* __restrict__ out)
{
  __shared__ uint4 smem4[LDS_BYTES/16];
  const int tid=threadIdx.x, lane=tid&63, wv=tid>>6;
  const int bz=blockIdx.z, d=bz>>1, b=bz&1;
  const int p0=blockIdx.x*9, y0=blockIdx.y;

  // --- weights -> LDS rows [go][k] (456 elems = 912B, zero-padded k>=432) ---
  unsigned short* wl=(unsigned short*)smem4;
  for(int idx=tid; idx<16*456; idx+=256) wl[idx]=0;
  __syncthreads();
  const float* wd=w_all+(long)d*16*16*27;
  for(int idx=tid; idx<16*432; idx+=256){
    int go=idx/432, r=idx-go*432, gi=r/27, tap=r-gi*27;
    wl[go*456+tap*16+gi]=f2bf(wd[(go*16+gi)*27+tap]);
  }
  __syncthreads();

  const int n=lane&15, kg=lane>>4, chunk=kg&1, hi=kg>>1;
  short8v bfr[14];
  {
    const unsigned short* base=wl+n*456+kg*8;
#pragma unroll
    for(int s=0;s<14;++s) bfr[s]=*(const short8v*)(base+s*32);
  }
  __syncthreads();   // done with wl; LDS reused for A tile

  // --- stage A tile (swizzled source -> linear LDS dest) ---
  {
    const unsigned short* slab=ws+(long)bz*SLABE;
    char* smemb=(char*)smem4;
#pragma unroll
    for(int it=0; it<18; ++it){
      int slot=it*256+tid;
      int sc=slot>4355?4355:slot;          // clamp tail (duplicate read, LDS in-bounds)
      unsigned S=(unsigned)sc*16u;
      unsigned L=S^(((S>>7)&7u)<<4);       // involution; bits 7-9 untouched
      unsigned pix=L>>5, ck=(L>>4)&1u;
      unsigned pp=pix/198u, r=pix-pp*198u; // tile rows of 3*66=198 pixels, contiguous in slab
      const char* gp=(const char*)slab
        + ((long)(p0+(int)pp)*PIX2+(long)y0*X2+r)*32 + ck*16;
      char* lp=smemb+(it*256+(tid&~63))*16;   // wave-uniform base; HW adds lane*16
      __builtin_amdgcn_global_load_lds(
        (const __attribute__((address_space(1))) void*)gp,
        (__attribute__((address_space(3))) void*)lp, 16, 0, 0);
    }
  }
  __syncthreads();

  // --- fused bias+BN constants for this lane's channel n ---
  const float scl=gamma_all[d*16+n]*rsqrtf(var_all[d*16+n]+1e-5f);
  const float ofs=(bias_all[d*16+n]-mean_all[d*16+n])*scl+beta_all[d*16+n];

  const char* sm=(const char*)smem4;
  const int x0=wv*16;
  const int mrow0=kg*4;

#pragma unroll
  for(int pg=0; pg<9; pg+=3){
    f32x4 ac0={0,0,0,0},ac1={0,0,0,0},ac2={0,0,0,0};
    const unsigned LB0=((pg+0)*198+x0+n)*32+chunk*16;
    const unsigned LB1=((pg+1)*198+x0+n)*32+chunk*16;
    const unsigned LB2=((pg+2)*198+x0+n)*32+chunk*16;
#pragma unroll
    for(int s=0;s<14;++s){
      const int t0=2*s, t1v=2*s+1;
      const int o0=((t0/9)*198+((t0%9)/3)*66+(t0%3))*32;
      const int o1=(t1v>26)?0:(((t1v/9)*198+((t1v%9)/3)*66+(t1v%3))*32);
      const int osel=hi?o1:o0;             // upper lane-half holds tap 2s+1
      unsigned L,S_;
      L=LB0+osel; S_=L^(((L>>7)&7u)<<4);
      short8v a0=*(const short8v*)(sm+S_);
      L=LB1+osel; S_=L^(((L>>7)&7u)<<4);
      short8v a1v=*(const short8v*)(sm+S_);
      L=LB2+osel; S_=L^(((L>>7)&7u)<<4);
      short8v a2v=*(const short8v*)(sm+S_);
      ac0=__builtin_amdgcn_mfma_f32_16x16x32_bf16(a0 ,bfr[s],ac0,0,0,0);
      ac1=__builtin_amdgcn_mfma_f32_16x16x32_bf16(a1v,bfr[s],ac1,0,0,0);
      ac2=__builtin_amdgcn_mfma_f32_16x16x32_bf16(a2v,bfr[s],ac2,0,0,0);
    }
#pragma unroll
    for(int jj=0;jj<3;++jj){
      f32x4 a=(jj==0)?ac0:((jj==1)?ac1:ac2);
      const int p=p0+pg+jj;
      float* ob=out+(((long)(b*64+d*16+n)*81+p)*4096)+y0*64+x0+mrow0;
#pragma unroll
      for(int rr=0;rr<4;++rr){
        float vv=fmaf(a[rr],scl,ofs);
        ob[rr]=vv>0.f?vv:0.f;
      }
    }
  }
}

extern "C" void kernel_launch(void* const* d_in, const int* in_sizes, int n_in,
                              void* d_out, int out_size, void* d_ws, size_t ws_size,
                              hipStream_t stream) {
  const float* x    = (const float*)d_in[0];
  const float* nbx  = (const float*)d_in[1];
  const float* cw   = (const float*)d_in[2];
  const float* cbia = (const float*)d_in[3];
  const float* gam  = (const float*)d_in[4];
  const float* bet  = (const float*)d_in[5];
  const float* mea  = (const float*)d_in[6];
  const float* var  = (const float*)d_in[7];
  float* out = (float*)d_out;
  unsigned short* ws16 = (unsigned short*)d_ws;   // 8 slabs * 11.57 MB = 92.6 MB (< ws)

  zero_border<<<dim3((8*P2*PIX2+255)/256),dim3(256),0,stream>>>(ws16);
  corr_kernel<<<dim3(64,8,3),dim3(64,4),0,stream>>>(x,nbx,ws16);
  conv_mfma<<<dim3(9,64,8),dim3(256),0,stream>>>(ws16,cw,cbia,gam,bet,mea,var,out);
}